// Round 2
// baseline (1325.351 us; speedup 1.0000x reference)
//
#include <hip/hip_runtime.h>
#include <hip/hip_bf16.h>

#define EPS 1e-5f

// ---------------------------------------------------------------- stats ----
// One block per (b,c); reduce mean & rstd over 32768 spatial elements.
__global__ __launch_bounds__(256) void stats_kernel(
    const float* __restrict__ buf, float* __restrict__ mean,
    float* __restrict__ rstd) {
  int bc = blockIdx.x;
  const float* ch = buf + (size_t)bc * 32768;
  float s = 0.f, ss = 0.f;
  for (int i = threadIdx.x; i < 32768; i += 256) {
    float v = ch[i];
    s += v; ss += v * v;
  }
  for (int o = 32; o; o >>= 1) {
    s += __shfl_down(s, o);
    ss += __shfl_down(ss, o);
  }
  __shared__ float sb[4], ssb[4];
  int wid = threadIdx.x >> 6, lane = threadIdx.x & 63;
  if (lane == 0) { sb[wid] = s; ssb[wid] = ss; }
  __syncthreads();
  if (threadIdx.x == 0) {
    float S = 0.f, SS = 0.f;
    for (int w = 0; w < 4; ++w) { S += sb[w]; SS += ssb[w]; }
    float m = S * (1.f / 32768.f);
    float var = SS * (1.f / 32768.f) - m * m;
    mean[bc] = m;
    rstd[bc] = rsqrtf(var + EPS);
  }
}

// ------------------------------------------------------------------- SE ----
__global__ void se_kernel(const float* __restrict__ mean_x,
                          const float* __restrict__ w1, const float* __restrict__ b1,
                          const float* __restrict__ w2, const float* __restrict__ b2,
                          float* __restrict__ dw) {
  __shared__ float hbuf[32];
  int t = threadIdx.x;
  if (t < 32) {
    int b = t >> 4, j = t & 15;
    float a = b1[j];
    for (int c = 0; c < 64; ++c) a += mean_x[b * 64 + c] * w1[j * 64 + c];
    hbuf[t] = a >= 0.f ? a : 0.2f * a;
  }
  __syncthreads();
  if (t < 2) {
    int b = t;
    float l0 = b2[0], l1 = b2[1];
    for (int j = 0; j < 16; ++j) {
      float h = hbuf[b * 16 + j];
      l0 += h * w2[j];
      l1 += h * w2[16 + j];
    }
    float m = fmaxf(l0, l1);
    float e0 = __expf(l0 - m), e1 = __expf(l1 - m);
    float inv = 1.f / (e0 + e1);
    dw[b * 2 + 0] = e0 * inv;
    dw[b * 2 + 1] = e1 * inv;
  }
}

// ------------------------------------------- fused inorm+lrelu+1x1 (64->32)
__global__ __launch_bounds__(256) void first_conv_kernel(
    const float* __restrict__ x, const float* __restrict__ w,   // [32,64]
    const float* __restrict__ bias,
    const float* __restrict__ meanp, const float* __restrict__ rstdp,
    float* __restrict__ f_cp, float* __restrict__ f_pc) {
  __shared__ float wT[64 * 32];  // wT[i][o]
  int tid = threadIdx.x;
  for (int idx = tid; idx < 2048; idx += 256) {
    int i = idx >> 5, o = idx & 31;
    wT[idx] = w[o * 64 + i];
  }
  __syncthreads();
  int vg = blockIdx.x * 256 + tid;
  int b = vg >> 15, p = vg & 32767;
  float acc[32];
#pragma unroll
  for (int o = 0; o < 32; ++o) acc[o] = 0.f;
  const float* xb = x + ((size_t)b * 64) * 32768;
  for (int i = 0; i < 64; ++i) {
    float v = xb[(size_t)i * 32768 + p];
    float m = meanp[b * 64 + i], r = rstdp[b * 64 + i];
    v = (v - m) * r;
    v = v >= 0.f ? v : 0.2f * v;
#pragma unroll
    for (int o = 0; o < 32; ++o) acc[o] += wT[i * 32 + o] * v;
  }
  float* pc = f_pc + ((size_t)b * 32768 + p) * 32;
#pragma unroll
  for (int o = 0; o < 32; ++o) {
    float val = acc[o] + bias[o];
    f_cp[((size_t)b * 32 + o) * 32768 + p] = val;
    pc[o] = val;
  }
}

// ----------------------------------------------------- tiled 3x3x3 conv ----
// Spatial tile 4x8x8 (z,y,x), halo 6x10x10 staged per input channel.
// NORM_IN: apply inorm+lrelu while staging (alpha branch).
// REFLECT: reflect padding (alpha) vs zero padding (offset conv).
template <int OCG, bool REFLECT, bool NORM_IN>
__global__ __launch_bounds__(256) void conv3_kernel(
    const float* __restrict__ in,    // [B,IC,32768]
    const float* __restrict__ w,     // [OC_total,IC,27]
    const float* __restrict__ bias,  // [OC_total]
    const float* __restrict__ meanp, const float* __restrict__ rstdp,
    float* __restrict__ out,         // [B,OC_total,32768]
    int IC, int OC_total) {
  int bid = blockIdx.x;
  int tile = bid & 127;
  int rem = bid >> 7;
  int b = rem & 1;
  int og = rem >> 1;
  int tz = tile >> 4, ty = (tile >> 2) & 3, tx = tile & 3;
  int z0 = tz * 4, y0 = ty * 8, x0 = tx * 8;

  int tid = threadIdx.x;
  int lz = tid >> 6, ly = (tid >> 3) & 7, lx = tid & 7;

  __shared__ float tileS[600];       // 6*10*10
  __shared__ float wS[OCG * 28];     // padded rows

  float acc[OCG];
#pragma unroll
  for (int o = 0; o < OCG; ++o) acc[o] = 0.f;

  const float* inb = in + ((size_t)b * IC) * 32768;

  for (int ic = 0; ic < IC; ++ic) {
    const float* ch = inb + (size_t)ic * 32768;
    float m = 0.f, r = 1.f;
    if (NORM_IN) { m = meanp[b * IC + ic]; r = rstdp[b * IC + ic]; }
    for (int idx = tid; idx < 600; idx += 256) {
      int hz = idx / 100, hy = (idx / 10) % 10, hx = idx % 10;
      int gz = z0 + hz - 1, gy = y0 + hy - 1, gx = x0 + hx - 1;
      float v;
      if (REFLECT) {
        gz = gz < 0 ? -gz : (gz > 31 ? 62 - gz : gz);
        gy = gy < 0 ? -gy : (gy > 31 ? 62 - gy : gy);
        gx = gx < 0 ? -gx : (gx > 31 ? 62 - gx : gx);
        v = ch[(gz * 32 + gy) * 32 + gx];
      } else {
        bool ok = (unsigned)gz < 32u && (unsigned)gy < 32u && (unsigned)gx < 32u;
        v = ok ? ch[(gz * 32 + gy) * 32 + gx] : 0.f;
      }
      if (NORM_IN) {
        v = (v - m) * r;
        v = v >= 0.f ? v : 0.2f * v;
      }
      tileS[idx] = v;
    }
    for (int idx = tid; idx < OCG * 27; idx += 256) {
      int o = idx / 27, t = idx % 27;
      wS[o * 28 + t] = w[((size_t)(og * OCG + o) * IC + ic) * 27 + t];
    }
    __syncthreads();
    float tap[27];
#pragma unroll
    for (int t = 0; t < 27; ++t) {
      int dz = t / 9, dy = (t / 3) % 3, dx = t % 3;
      tap[t] = tileS[((lz + dz) * 10 + (ly + dy)) * 10 + (lx + dx)];
    }
#pragma unroll
    for (int o = 0; o < OCG; ++o) {
#pragma unroll
      for (int t = 0; t < 27; ++t) acc[o] += wS[o * 28 + t] * tap[t];
    }
    __syncthreads();
  }
  int p = ((z0 + lz) * 32 + (y0 + ly)) * 32 + (x0 + lx);
#pragma unroll
  for (int o = 0; o < OCG; ++o) {
    int oc = og * OCG + o;
    out[((size_t)b * OC_total + oc) * 32768 + p] = acc[o] + bias[oc];
  }
}

// --------------------------------------------------------------- deform ----
// 3-way split over the 27 taps (kg=0..2 handles 9 taps) for occupancy.
__global__ __launch_bounds__(256) void deform_kernel(
    const float* __restrict__ f_pc,  // [B,32768,32]
    const float* __restrict__ offs,  // [B,81,32768]
    const float* __restrict__ wdef,  // [32,32,27]
    float* __restrict__ part) {      // [3,B,32,32768]
  int bid = blockIdx.x;
  int kg = bid >> 8;
  int tile = bid & 255;
  int vg = tile * 256 + threadIdx.x;
  int b = vg >> 15, p = vg & 32767;
  int z = p >> 10, y = (p >> 5) & 31, x = p & 31;
  __shared__ float wk[1024];  // wk[o*32+i] for current tap
  float acc[32];
#pragma unroll
  for (int o = 0; o < 32; ++o) acc[o] = 0.f;
  const float* fb = f_pc + (((size_t)b) << 15) * 32;
  const float* offb = offs + (((size_t)b * 81) << 15);

  for (int kk = 0; kk < 9; ++kk) {
    int k = kg * 9 + kk;
    for (int idx = threadIdx.x; idx < 1024; idx += 256)
      wk[idx] = wdef[idx * 27 + k];
    __syncthreads();

    float oz = offb[(size_t)(k * 3 + 0) * 32768 + p];
    float oy = offb[(size_t)(k * 3 + 1) * 32768 + p];
    float ox = offb[(size_t)(k * 3 + 2) * 32768 + p];
    float pz = (float)(z + (k / 9) - 1) + oz;
    float py = (float)(y + ((k / 3) % 3) - 1) + oy;
    float px = (float)(x + (k % 3) - 1) + ox;
    float fz = floorf(pz), fy = floorf(py), fx = floorf(px);
    int iz0 = (int)fz, iy0 = (int)fy, ix0 = (int)fx;
    float rz = pz - fz, ry = py - fy, rx = px - fx;

    float v[32];
#pragma unroll
    for (int c = 0; c < 32; ++c) v[c] = 0.f;
#pragma unroll
    for (int corner = 0; corner < 8; ++corner) {
      int dz = corner >> 2, dy = (corner >> 1) & 1, dx = corner & 1;
      int iz = iz0 + dz, iy = iy0 + dy, ix = ix0 + dx;
      bool ok = (unsigned)iz < 32u && (unsigned)iy < 32u && (unsigned)ix < 32u;
      float wt = (dz ? rz : 1.f - rz) * (dy ? ry : 1.f - ry) * (dx ? rx : 1.f - rx);
      if (ok && wt != 0.f) {
        const float4* src = (const float4*)(fb + (size_t)((iz * 32 + iy) * 32 + ix) * 32);
#pragma unroll
        for (int q = 0; q < 8; ++q) {
          float4 u = src[q];
          v[q * 4 + 0] += wt * u.x;
          v[q * 4 + 1] += wt * u.y;
          v[q * 4 + 2] += wt * u.z;
          v[q * 4 + 3] += wt * u.w;
        }
      }
    }
#pragma unroll
    for (int o = 0; o < 32; ++o) {
      float a = 0.f;
#pragma unroll
      for (int i = 0; i < 32; ++i) a += wk[o * 32 + i] * v[i];
      acc[o] += a;
    }
    __syncthreads();
  }
  float* ob = part + (((size_t)kg * 2 + b) * 32) * 32768;
#pragma unroll
  for (int o = 0; o < 32; ++o) ob[(size_t)o * 32768 + p] = acc[o];
}

// -------------------------------------------- combine + stats of comb -----
__global__ __launch_bounds__(256) void combine_kernel(
    const float* __restrict__ part, const float* __restrict__ alpha,
    const float* __restrict__ dw, float* __restrict__ comb,
    float* __restrict__ mean, float* __restrict__ rstd) {
  int bc = blockIdx.x;  // b*32+c
  int b = bc >> 5;
  float d0 = dw[b * 2 + 0], d1 = dw[b * 2 + 1];
  const float* p0 = part + (size_t)(bc) * 32768;
  const float* p1 = part + (size_t)(64 + bc) * 32768;
  const float* p2 = part + (size_t)(128 + bc) * 32768;
  const float* al = alpha + (size_t)bc * 32768;
  float* cb = comb + (size_t)bc * 32768;
  float s = 0.f, ss = 0.f;
  for (int i = threadIdx.x; i < 32768; i += 256) {
    float v = d0 * (p0[i] + p1[i] + p2[i]) + d1 * al[i];
    cb[i] = v;
    s += v; ss += v * v;
  }
  for (int o = 32; o; o >>= 1) {
    s += __shfl_down(s, o);
    ss += __shfl_down(ss, o);
  }
  __shared__ float sb[4], ssb[4];
  int wid = threadIdx.x >> 6, lane = threadIdx.x & 63;
  if (lane == 0) { sb[wid] = s; ssb[wid] = ss; }
  __syncthreads();
  if (threadIdx.x == 0) {
    float S = 0.f, SS = 0.f;
    for (int w = 0; w < 4; ++w) { S += sb[w]; SS += ssb[w]; }
    float m = S * (1.f / 32768.f);
    float var = SS * (1.f / 32768.f) - m * m;
    mean[bc] = m;
    rstd[bc] = rsqrtf(var + EPS);
  }
}

// ------------------------------------------- fused inorm+lrelu+1x1 (32->32)
__global__ __launch_bounds__(256) void last_conv_kernel(
    const float* __restrict__ comb, const float* __restrict__ w,  // [32,32]
    const float* __restrict__ bias,
    const float* __restrict__ meanp, const float* __restrict__ rstdp,
    float* __restrict__ out) {
  __shared__ float wT[1024];  // wT[i][o]
  int tid = threadIdx.x;
  for (int idx = tid; idx < 1024; idx += 256) {
    int i = idx >> 5, o = idx & 31;
    wT[idx] = w[o * 32 + i];
  }
  __syncthreads();
  int vg = blockIdx.x * 256 + tid;
  int b = vg >> 15, p = vg & 32767;
  float acc[32];
#pragma unroll
  for (int o = 0; o < 32; ++o) acc[o] = 0.f;
  const float* cb = comb + ((size_t)b * 32) * 32768;
  for (int i = 0; i < 32; ++i) {
    float v = cb[(size_t)i * 32768 + p];
    float m = meanp[b * 32 + i], r = rstdp[b * 32 + i];
    v = (v - m) * r;
    v = v >= 0.f ? v : 0.2f * v;
#pragma unroll
    for (int o = 0; o < 32; ++o) acc[o] += wT[i * 32 + o] * v;
  }
#pragma unroll
  for (int o = 0; o < 32; ++o)
    out[((size_t)b * 32 + o) * 32768 + p] = acc[o] + bias[o];
}

// ---------------------------------------------------------------- launch ---
extern "C" void kernel_launch(void* const* d_in, const int* in_sizes, int n_in,
                              void* d_out, int out_size, void* d_ws, size_t ws_size,
                              hipStream_t stream) {
  (void)in_sizes; (void)n_in; (void)out_size; (void)ws_size;
  const float* x       = (const float*)d_in[0];
  const float* w_first = (const float*)d_in[1];
  const float* b_first = (const float*)d_in[2];
  const float* w_na    = (const float*)d_in[3];
  const float* b_na    = (const float*)d_in[4];
  const float* w_last  = (const float*)d_in[5];
  const float* b_last  = (const float*)d_in[6];
  const float* w_fc1   = (const float*)d_in[7];
  const float* b_fc1   = (const float*)d_in[8];
  const float* w_fc2   = (const float*)d_in[9];
  const float* b_fc2   = (const float*)d_in[10];
  const float* w_off   = (const float*)d_in[11];
  const float* b_off   = (const float*)d_in[12];
  const float* w_def   = (const float*)d_in[13];
  float* out = (float*)d_out;

  float* ws = (float*)d_ws;
  // workspace layout (floats)
  float* mean_x = ws + 0;        // 128
  float* rstd_x = ws + 128;      // 128
  float* dwp    = ws + 256;      // 4
  float* mean_f = ws + 272;      // 64
  float* rstd_f = ws + 336;      // 64
  float* mean_c = ws + 400;      // 64
  float* rstd_c = ws + 464;      // 64
  size_t off0 = 1024;
  float* f_cp  = ws + off0;                       // 2,097,152
  float* f_pc  = f_cp + 2097152;                  // 2,097,152
  float* offb  = f_pc + 2097152;                  // 5,308,416
  float* alpha = offb + 5308416;                  // 2,097,152
  float* part  = alpha + 2097152;                 // 6,291,456
  float* comb  = part + 6291456;                  // 2,097,152

  // 1. stats of x (also SE's global average pool)
  hipLaunchKernelGGL(stats_kernel, dim3(128), dim3(256), 0, stream, x, mean_x, rstd_x);
  // 2. SE gate -> dw[2,2]
  hipLaunchKernelGGL(se_kernel, dim3(1), dim3(64), 0, stream,
                     mean_x, w_fc1, b_fc1, w_fc2, b_fc2, dwp);
  // 3. f = conv1x1(lrelu(inorm(x))) + b  (two layouts)
  hipLaunchKernelGGL(first_conv_kernel, dim3(256), dim3(256), 0, stream,
                     x, w_first, b_first, mean_x, rstd_x, f_cp, f_pc);
  // 4. stats of f (for alpha branch inorm)
  hipLaunchKernelGGL(stats_kernel, dim3(64), dim3(256), 0, stream, f_cp, mean_f, rstd_f);
  // 5. off = conv3x3x3(f), zero pad, 32->81 (3 oc-groups of 27)
  hipLaunchKernelGGL((conv3_kernel<27, false, false>), dim3(128 * 2 * 3), dim3(256), 0, stream,
                     f_cp, w_off, b_off, nullptr, nullptr, offb, 32, 81);
  // 6. alpha = conv3x3x3(lrelu(inorm(f))), reflect pad, 32->32
  hipLaunchKernelGGL((conv3_kernel<32, true, true>), dim3(128 * 2), dim3(256), 0, stream,
                     f_cp, w_na, b_na, mean_f, rstd_f, alpha, 32, 32);
  // 7. belta partials (3 tap-groups)
  hipLaunchKernelGGL(deform_kernel, dim3(768), dim3(256), 0, stream,
                     f_pc, offb, w_def, part);
  // 8. comb = dw0*belta + dw1*alpha, + stats of comb
  hipLaunchKernelGGL(combine_kernel, dim3(64), dim3(256), 0, stream,
                     part, alpha, dwp, comb, mean_c, rstd_c);
  // 9. out = conv1x1(lrelu(inorm(comb))) + b_last
  hipLaunchKernelGGL(last_conv_kernel, dim3(256), dim3(256), 0, stream,
                     comb, w_last, b_last, mean_c, rstd_c, out);
}

// Round 3
// 944.241 us; speedup vs baseline: 1.4036x; 1.4036x over previous
//
#include <hip/hip_runtime.h>
#include <hip/hip_bf16.h>

#define EPS 1e-5f

// ---------------------------------------------------------------- stats ----
__global__ __launch_bounds__(256) void stats_kernel(
    const float* __restrict__ buf, float* __restrict__ mean,
    float* __restrict__ rstd) {
  int bc = blockIdx.x;
  const float* ch = buf + (size_t)bc * 32768;
  float s = 0.f, ss = 0.f;
  for (int i = threadIdx.x; i < 32768; i += 256) {
    float v = ch[i];
    s += v; ss += v * v;
  }
  for (int o = 32; o; o >>= 1) {
    s += __shfl_down(s, o);
    ss += __shfl_down(ss, o);
  }
  __shared__ float sb[4], ssb[4];
  int wid = threadIdx.x >> 6, lane = threadIdx.x & 63;
  if (lane == 0) { sb[wid] = s; ssb[wid] = ss; }
  __syncthreads();
  if (threadIdx.x == 0) {
    float S = 0.f, SS = 0.f;
    for (int w = 0; w < 4; ++w) { S += sb[w]; SS += ssb[w]; }
    float m = S * (1.f / 32768.f);
    float var = SS * (1.f / 32768.f) - m * m;
    mean[bc] = m;
    rstd[bc] = rsqrtf(var + EPS);
  }
}

// ------------------------------------------------------------------- SE ----
__global__ void se_kernel(const float* __restrict__ mean_x,
                          const float* __restrict__ w1, const float* __restrict__ b1,
                          const float* __restrict__ w2, const float* __restrict__ b2,
                          float* __restrict__ dw) {
  __shared__ float hbuf[32];
  int t = threadIdx.x;
  if (t < 32) {
    int b = t >> 4, j = t & 15;
    float a = b1[j];
    for (int c = 0; c < 64; ++c) a += mean_x[b * 64 + c] * w1[j * 64 + c];
    hbuf[t] = a >= 0.f ? a : 0.2f * a;
  }
  __syncthreads();
  if (t < 2) {
    int b = t;
    float l0 = b2[0], l1 = b2[1];
    for (int j = 0; j < 16; ++j) {
      float h = hbuf[b * 16 + j];
      l0 += h * w2[j];
      l1 += h * w2[16 + j];
    }
    float m = fmaxf(l0, l1);
    float e0 = __expf(l0 - m), e1 = __expf(l1 - m);
    float inv = 1.f / (e0 + e1);
    dw[b * 2 + 0] = e0 * inv;
    dw[b * 2 + 1] = e1 * inv;
  }
}

// ------------------------------------------- fused inorm+lrelu+1x1 (64->32)
__global__ __launch_bounds__(256) void first_conv_kernel(
    const float* __restrict__ x, const float* __restrict__ w,   // [32,64]
    const float* __restrict__ bias,
    const float* __restrict__ meanp, const float* __restrict__ rstdp,
    float* __restrict__ f_cp, float* __restrict__ f_pc) {
  __shared__ float wT[64 * 32];  // wT[i][o]
  int tid = threadIdx.x;
  for (int idx = tid; idx < 2048; idx += 256) {
    int i = idx >> 5, o = idx & 31;
    wT[idx] = w[o * 64 + i];
  }
  __syncthreads();
  int vg = blockIdx.x * 256 + tid;
  int b = vg >> 15, p = vg & 32767;
  float acc[32];
#pragma unroll
  for (int o = 0; o < 32; ++o) acc[o] = 0.f;
  const float* xb = x + ((size_t)b * 64) * 32768;
  for (int i = 0; i < 64; ++i) {
    float v = xb[(size_t)i * 32768 + p];
    float m = meanp[b * 64 + i], r = rstdp[b * 64 + i];
    v = (v - m) * r;
    v = v >= 0.f ? v : 0.2f * v;
#pragma unroll
    for (int o = 0; o < 32; ++o) acc[o] += wT[i * 32 + o] * v;
  }
  float* pc = f_pc + ((size_t)b * 32768 + p) * 32;
#pragma unroll
  for (int o = 0; o < 32; ++o) {
    float val = acc[o] + bias[o];
    f_cp[((size_t)b * 32 + o) * 32768 + p] = val;
    pc[o] = val;
  }
}

// ----------------------------------------------------- tiled 3x3x3 conv ----
// Spatial tile 4x8x8 (z,y,x). Halo 6x10x10 staged in LDS with pitch-12 rows
// (uniform 2-way bank access = free). Weights read as wave-uniform scalar
// loads (SGPR operand to v_fmac) -- no LDS weight traffic. Double-buffered
// staging, one barrier per ic. Staging address math (incl. reflect mapping)
// hoisted out of the ic loop, fully statically indexed.
template <int OCG, bool REFLECT, bool NORM_IN>
__global__ __launch_bounds__(256) void conv3_kernel(
    const float* __restrict__ in,    // [B,IC,32768]
    const float* __restrict__ w,     // [OC_total,IC,27]
    const float* __restrict__ bias,  // [OC_total]
    const float* __restrict__ meanp, const float* __restrict__ rstdp,
    float* __restrict__ out,         // [B,OC_total,32768]
    int IC, int OC_total) {
  int bid = blockIdx.x;
  int tile = bid & 127;
  int rem = bid >> 7;
  int b = rem & 1;
  int og = rem >> 1;
  int tz = tile >> 4, ty = (tile >> 2) & 3, tx = tile & 3;
  int z0 = tz * 4, y0 = ty * 8, x0 = tx * 8;

  int tid = threadIdx.x;
  int lz = tid >> 6, ly = (tid >> 3) & 7, lx = tid & 7;

  __shared__ float tileS[2][720];  // [6][10][12]

  // --- per-thread staging descriptors (ic-invariant), 3 static slots ---
  int s0 = tid, s1 = tid + 256, s2 = tid + 512;
  int g0 = 0, g1 = 0, g2 = 0;
  bool a0 = false, a1 = false, a2 = false;  // active (load & write)
  bool k0 = true, k1 = true, k2 = true;     // in-bounds (zero-pad mode)
#define DESC(S, G, A, K)                                            \
  {                                                                 \
    int hz = (S) / 120;                                             \
    int rr = (S) - hz * 120;                                        \
    int hy = rr / 12;                                               \
    int hx = rr - hy * 12;                                          \
    if ((S) < 720 && hx < 10) {                                     \
      int gz = z0 + hz - 1, gy = y0 + hy - 1, gx = x0 + hx - 1;     \
      if (REFLECT) {                                                \
        gz = gz < 0 ? -gz : (gz > 31 ? 62 - gz : gz);               \
        gy = gy < 0 ? -gy : (gy > 31 ? 62 - gy : gy);               \
        gx = gx < 0 ? -gx : (gx > 31 ? 62 - gx : gx);               \
      } else {                                                      \
        K = (unsigned)gz < 32u && (unsigned)gy < 32u &&             \
            (unsigned)gx < 32u;                                     \
        if (!(K)) { gz = 0; gy = 0; gx = 0; }                       \
      }                                                             \
      G = (gz * 32 + gy) * 32 + gx;                                 \
      A = true;                                                     \
    }                                                               \
  }
  DESC(s0, g0, a0, k0)
  DESC(s1, g1, a1, k1)
  DESC(s2, g2, a2, k2)
#undef DESC

  const float* inb = in + ((size_t)b * IC) * 32768;
  int ocbase = og * OCG;

  float acc[OCG];
#pragma unroll
  for (int o = 0; o < OCG; ++o) acc[o] = 0.f;

#define STAGE(BUF, IC2)                                             \
  {                                                                 \
    const float* ch = inb + (size_t)(IC2) * 32768;                  \
    float m = 0.f, r = 1.f;                                         \
    if (NORM_IN) {                                                  \
      m = meanp[b * IC + (IC2)];                                    \
      r = rstdp[b * IC + (IC2)];                                    \
    }                                                               \
    float v;                                                        \
    if (a0) {                                                       \
      v = k0 ? ch[g0] : 0.f;                                        \
      if (NORM_IN) { v = (v - m) * r; v = v >= 0.f ? v : 0.2f * v; }\
      tileS[BUF][s0] = v;                                           \
    }                                                               \
    if (a1) {                                                       \
      v = k1 ? ch[g1] : 0.f;                                        \
      if (NORM_IN) { v = (v - m) * r; v = v >= 0.f ? v : 0.2f * v; }\
      tileS[BUF][s1] = v;                                           \
    }                                                               \
    if (a2) {                                                       \
      v = k2 ? ch[g2] : 0.f;                                        \
      if (NORM_IN) { v = (v - m) * r; v = v >= 0.f ? v : 0.2f * v; }\
      tileS[BUF][s2] = v;                                           \
    }                                                               \
  }

  STAGE(0, 0)
  __syncthreads();

  int base = lz * 120 + ly * 12 + lx;
  for (int ic = 0; ic < IC; ++ic) {
    int cur = ic & 1;
    if (ic + 1 < IC) STAGE(cur ^ 1, ic + 1)

    float tap[27];
#pragma unroll
    for (int t = 0; t < 27; ++t) {
      int dz = t / 9, dy = (t / 3) % 3, dx = t % 3;
      tap[t] = tileS[cur][base + dz * 120 + dy * 12 + dx];
    }
    const float* wic = w + (size_t)ic * 27;
#pragma unroll
    for (int o = 0; o < OCG; ++o) {
      const float* wo = wic + (size_t)(ocbase + o) * IC * 27;  // wave-uniform
#pragma unroll
      for (int t = 0; t < 27; ++t) acc[o] = fmaf(wo[t], tap[t], acc[o]);
    }
    __syncthreads();
  }
#undef STAGE

  int p = ((z0 + lz) * 32 + (y0 + ly)) * 32 + (x0 + lx);
#pragma unroll
  for (int o = 0; o < OCG; ++o) {
    int oc = ocbase + o;
    out[((size_t)b * OC_total + oc) * 32768 + p] = acc[o] + bias[oc];
  }
}

// --------------------------------------------------------------- deform ----
__global__ __launch_bounds__(256) void deform_kernel(
    const float* __restrict__ f_pc,  // [B,32768,32]
    const float* __restrict__ offs,  // [B,81,32768]
    const float* __restrict__ wdef,  // [32,32,27]
    float* __restrict__ part) {      // [3,B,32,32768]
  int bid = blockIdx.x;
  int kg = bid >> 8;
  int tile = bid & 255;
  int vg = tile * 256 + threadIdx.x;
  int b = vg >> 15, p = vg & 32767;
  int z = p >> 10, y = (p >> 5) & 31, x = p & 31;
  __shared__ float wk[1024];  // wk[o*32+i] for current tap
  float acc[32];
#pragma unroll
  for (int o = 0; o < 32; ++o) acc[o] = 0.f;
  const float* fb = f_pc + (((size_t)b) << 15) * 32;
  const float* offb = offs + (((size_t)b * 81) << 15);

  for (int kk = 0; kk < 9; ++kk) {
    int k = kg * 9 + kk;
    for (int idx = threadIdx.x; idx < 1024; idx += 256)
      wk[idx] = wdef[idx * 27 + k];
    __syncthreads();

    float oz = offb[(size_t)(k * 3 + 0) * 32768 + p];
    float oy = offb[(size_t)(k * 3 + 1) * 32768 + p];
    float ox = offb[(size_t)(k * 3 + 2) * 32768 + p];
    float pz = (float)(z + (k / 9) - 1) + oz;
    float py = (float)(y + ((k / 3) % 3) - 1) + oy;
    float px = (float)(x + (k % 3) - 1) + ox;
    float fz = floorf(pz), fy = floorf(py), fx = floorf(px);
    int iz0 = (int)fz, iy0 = (int)fy, ix0 = (int)fx;
    float rz = pz - fz, ry = py - fy, rx = px - fx;

    float v[32];
#pragma unroll
    for (int c = 0; c < 32; ++c) v[c] = 0.f;
#pragma unroll
    for (int corner = 0; corner < 8; ++corner) {
      int dz = corner >> 2, dy = (corner >> 1) & 1, dx = corner & 1;
      int iz = iz0 + dz, iy = iy0 + dy, ix = ix0 + dx;
      bool ok = (unsigned)iz < 32u && (unsigned)iy < 32u && (unsigned)ix < 32u;
      float wt = (dz ? rz : 1.f - rz) * (dy ? ry : 1.f - ry) * (dx ? rx : 1.f - rx);
      if (ok && wt != 0.f) {
        const float4* src = (const float4*)(fb + (size_t)((iz * 32 + iy) * 32 + ix) * 32);
#pragma unroll
        for (int q = 0; q < 8; ++q) {
          float4 u = src[q];
          v[q * 4 + 0] += wt * u.x;
          v[q * 4 + 1] += wt * u.y;
          v[q * 4 + 2] += wt * u.z;
          v[q * 4 + 3] += wt * u.w;
        }
      }
    }
#pragma unroll
    for (int o = 0; o < 32; ++o) {
      float a = 0.f;
#pragma unroll
      for (int i = 0; i < 32; ++i) a += wk[o * 32 + i] * v[i];
      acc[o] += a;
    }
    __syncthreads();
  }
  float* ob = part + (((size_t)kg * 2 + b) * 32) * 32768;
#pragma unroll
  for (int o = 0; o < 32; ++o) ob[(size_t)o * 32768 + p] = acc[o];
}

// -------------------------------------------- combine + stats of comb -----
__global__ __launch_bounds__(256) void combine_kernel(
    const float* __restrict__ part, const float* __restrict__ alpha,
    const float* __restrict__ dw, float* __restrict__ comb,
    float* __restrict__ mean, float* __restrict__ rstd) {
  int bc = blockIdx.x;  // b*32+c
  int b = bc >> 5;
  float d0 = dw[b * 2 + 0], d1 = dw[b * 2 + 1];
  const float* p0 = part + (size_t)(bc) * 32768;
  const float* p1 = part + (size_t)(64 + bc) * 32768;
  const float* p2 = part + (size_t)(128 + bc) * 32768;
  const float* al = alpha + (size_t)bc * 32768;
  float* cb = comb + (size_t)bc * 32768;
  float s = 0.f, ss = 0.f;
  for (int i = threadIdx.x; i < 32768; i += 256) {
    float v = d0 * (p0[i] + p1[i] + p2[i]) + d1 * al[i];
    cb[i] = v;
    s += v; ss += v * v;
  }
  for (int o = 32; o; o >>= 1) {
    s += __shfl_down(s, o);
    ss += __shfl_down(ss, o);
  }
  __shared__ float sb[4], ssb[4];
  int wid = threadIdx.x >> 6, lane = threadIdx.x & 63;
  if (lane == 0) { sb[wid] = s; ssb[wid] = ss; }
  __syncthreads();
  if (threadIdx.x == 0) {
    float S = 0.f, SS = 0.f;
    for (int w = 0; w < 4; ++w) { S += sb[w]; SS += ssb[w]; }
    float m = S * (1.f / 32768.f);
    float var = SS * (1.f / 32768.f) - m * m;
    mean[bc] = m;
    rstd[bc] = rsqrtf(var + EPS);
  }
}

// ------------------------------------------- fused inorm+lrelu+1x1 (32->32)
__global__ __launch_bounds__(256) void last_conv_kernel(
    const float* __restrict__ comb, const float* __restrict__ w,  // [32,32]
    const float* __restrict__ bias,
    const float* __restrict__ meanp, const float* __restrict__ rstdp,
    float* __restrict__ out) {
  __shared__ float wT[1024];  // wT[i][o]
  int tid = threadIdx.x;
  for (int idx = tid; idx < 1024; idx += 256) {
    int i = idx >> 5, o = idx & 31;
    wT[idx] = w[o * 32 + i];
  }
  __syncthreads();
  int vg = blockIdx.x * 256 + tid;
  int b = vg >> 15, p = vg & 32767;
  float acc[32];
#pragma unroll
  for (int o = 0; o < 32; ++o) acc[o] = 0.f;
  const float* cb = comb + ((size_t)b * 32) * 32768;
  for (int i = 0; i < 32; ++i) {
    float v = cb[(size_t)i * 32768 + p];
    float m = meanp[b * 32 + i], r = rstdp[b * 32 + i];
    v = (v - m) * r;
    v = v >= 0.f ? v : 0.2f * v;
#pragma unroll
    for (int o = 0; o < 32; ++o) acc[o] += wT[i * 32 + o] * v;
  }
#pragma unroll
  for (int o = 0; o < 32; ++o)
    out[((size_t)b * 32 + o) * 32768 + p] = acc[o] + bias[o];
}

// ---------------------------------------------------------------- launch ---
extern "C" void kernel_launch(void* const* d_in, const int* in_sizes, int n_in,
                              void* d_out, int out_size, void* d_ws, size_t ws_size,
                              hipStream_t stream) {
  (void)in_sizes; (void)n_in; (void)out_size; (void)ws_size;
  const float* x       = (const float*)d_in[0];
  const float* w_first = (const float*)d_in[1];
  const float* b_first = (const float*)d_in[2];
  const float* w_na    = (const float*)d_in[3];
  const float* b_na    = (const float*)d_in[4];
  const float* w_last  = (const float*)d_in[5];
  const float* b_last  = (const float*)d_in[6];
  const float* w_fc1   = (const float*)d_in[7];
  const float* b_fc1   = (const float*)d_in[8];
  const float* w_fc2   = (const float*)d_in[9];
  const float* b_fc2   = (const float*)d_in[10];
  const float* w_off   = (const float*)d_in[11];
  const float* b_off   = (const float*)d_in[12];
  const float* w_def   = (const float*)d_in[13];
  float* out = (float*)d_out;

  float* ws = (float*)d_ws;
  float* mean_x = ws + 0;        // 128
  float* rstd_x = ws + 128;      // 128
  float* dwp    = ws + 256;      // 4
  float* mean_f = ws + 272;      // 64
  float* rstd_f = ws + 336;      // 64
  float* mean_c = ws + 400;      // 64
  float* rstd_c = ws + 464;      // 64
  size_t off0 = 1024;
  float* f_cp  = ws + off0;                       // 2,097,152
  float* f_pc  = f_cp + 2097152;                  // 2,097,152
  float* offb  = f_pc + 2097152;                  // 5,308,416
  float* alpha = offb + 5308416;                  // 2,097,152
  float* part  = alpha + 2097152;                 // 6,291,456
  float* comb  = part + 6291456;                  // 2,097,152

  // 1. stats of x (also SE's global average pool)
  hipLaunchKernelGGL(stats_kernel, dim3(128), dim3(256), 0, stream, x, mean_x, rstd_x);
  // 2. SE gate -> dw[2,2]
  hipLaunchKernelGGL(se_kernel, dim3(1), dim3(64), 0, stream,
                     mean_x, w_fc1, b_fc1, w_fc2, b_fc2, dwp);
  // 3. f = conv1x1(lrelu(inorm(x))) + b  (two layouts)
  hipLaunchKernelGGL(first_conv_kernel, dim3(256), dim3(256), 0, stream,
                     x, w_first, b_first, mean_x, rstd_x, f_cp, f_pc);
  // 4. stats of f (for alpha branch inorm)
  hipLaunchKernelGGL(stats_kernel, dim3(64), dim3(256), 0, stream, f_cp, mean_f, rstd_f);
  // 5. off = conv3x3x3(f), zero pad, 32->81 (9 oc-groups of 9)
  hipLaunchKernelGGL((conv3_kernel<9, false, false>), dim3(128 * 2 * 9), dim3(256), 0, stream,
                     f_cp, w_off, b_off, nullptr, nullptr, offb, 32, 81);
  // 6. alpha = conv3x3x3(lrelu(inorm(f))), reflect pad, 32->32 (4 groups of 8)
  hipLaunchKernelGGL((conv3_kernel<8, true, true>), dim3(128 * 2 * 4), dim3(256), 0, stream,
                     f_cp, w_na, b_na, mean_f, rstd_f, alpha, 32, 32);
  // 7. belta partials (3 tap-groups)
  hipLaunchKernelGGL(deform_kernel, dim3(768), dim3(256), 0, stream,
                     f_pc, offb, w_def, part);
  // 8. comb = dw0*belta + dw1*alpha, + stats of comb
  hipLaunchKernelGGL(combine_kernel, dim3(64), dim3(256), 0, stream,
                     part, alpha, dwp, comb, mean_c, rstd_c);
  // 9. out = conv1x1(lrelu(inorm(comb))) + b_last
  hipLaunchKernelGGL(last_conv_kernel, dim3(256), dim3(256), 0, stream,
                     comb, w_last, b_last, mean_c, rstd_c, out);
}